// Round 3
// baseline (1333.970 us; speedup 1.0000x reference)
//
#include <hip/hip_runtime.h>

#define E_TOTAL 800000
#define NN 50000
#define WT_U16 122880          // total bf16 weight elements (8 matrices)
#define WT_BYTES (WT_U16 * 2)  // 245760, 16-byte aligned size

typedef unsigned short u16;
typedef short short8 __attribute__((ext_vector_type(8)));
typedef float floatx4 __attribute__((ext_vector_type(4)));

__device__ __forceinline__ u16 f2bf(float f) {
    union { float f; unsigned int i; } x; x.f = f;
    unsigned int i = x.i;
    return (u16)((i + 0x7FFFu + ((i >> 16) & 1u)) >> 16);  // RNE
}
__device__ __forceinline__ unsigned int pack2(float a, float b) {
    return (unsigned int)f2bf(a) | ((unsigned int)f2bf(b) << 16);
}
// load float4, convert to 4 bf16 packed in uint2
__device__ __forceinline__ uint2 cvt4(const float* p) {
    float4 v = *(const float4*)p;
    uint2 r; r.x = pack2(v.x, v.y); r.y = pack2(v.z, v.w);
    return r;
}
__device__ __forceinline__ uint2 packf4(floatx4 v) {
    uint2 r; r.x = pack2(v[0], v[1]); r.y = pack2(v[2], v[3]);
    return r;
}

// ---- one MLP layer on a 16-row slab owned by one wave --------------------
// lds_in/lds_out: wave slab base (bf16). wt: [N][K] bf16 k-contig. bias: f32.
template<int K, int N, bool RELU>
__device__ __forceinline__ void layer_slab(const u16* lds_in, int in_stride,
                                           u16* lds_out, int out_stride,
                                           const u16* __restrict__ wt,
                                           const float* __restrict__ bias,
                                           int lane)
{
    const int m = lane & 15, quad = lane >> 4;
    short8 a[K / 32];
#pragma unroll
    for (int kb = 0; kb < K / 32; ++kb)
        a[kb] = *(const short8*)(lds_in + m * in_stride + kb * 32 + quad * 8);
#pragma unroll
    for (int nt = 0; nt < N / 16; nt += 2) {
        floatx4 acc0 = {0.f, 0.f, 0.f, 0.f}, acc1 = {0.f, 0.f, 0.f, 0.f};
        const int n0 = nt * 16 + m, n1 = n0 + 16;
        const u16* w0 = wt + n0 * K + quad * 8;
        const u16* w1 = wt + n1 * K + quad * 8;
#pragma unroll
        for (int kb = 0; kb < K / 32; ++kb) {
            short8 b0 = *(const short8*)(w0 + kb * 32);
            short8 b1 = *(const short8*)(w1 + kb * 32);
            acc0 = __builtin_amdgcn_mfma_f32_16x16x32_bf16(a[kb], b0, acc0, 0, 0, 0);
            acc1 = __builtin_amdgcn_mfma_f32_16x16x32_bf16(a[kb], b1, acc1, 0, 0, 0);
        }
        float bb0 = bias[n0], bb1 = bias[n1];
#pragma unroll
        for (int r = 0; r < 4; ++r) {
            int row = quad * 4 + r;
            float v0 = acc0[r] + bb0, v1 = acc1[r] + bb1;
            if (RELU) { v0 = fmaxf(v0, 0.f); v1 = fmaxf(v1, 0.f); }
            lds_out[row * out_stride + n0] = f2bf(v0);
            lds_out[row * out_stride + n1] = f2bf(v1);
        }
    }
}

// ---- weight prep: W[k][n] f32 -> Wt[n][k] bf16, all 8 matrices ------------
__global__ __launch_bounds__(256) void prep_wt(
    const float* __restrict__ e0, const float* __restrict__ e1,
    const float* __restrict__ e2, const float* __restrict__ e3,
    const float* __restrict__ m0, const float* __restrict__ m1,
    const float* __restrict__ m2, const float* __restrict__ m3,
    u16* __restrict__ dst)
{
    int t = blockIdx.x * 256 + threadIdx.x;
    if (t >= WT_U16) return;
    const int offs[9] = {0, 24576, 40960, 57344, 65536, 81920, 98304, 114688, 122880};
    const int Ks[8]   = {192, 128, 128, 128, 128, 128, 128, 128};
    const int Ns[8]   = {128, 128, 128,  64, 128, 128, 128,  64};
    const float* srcs[8] = {e0, e1, e2, e3, m0, m1, m2, m3};
    int s = 0;
    while (t >= offs[s + 1]) ++s;
    int e = t - offs[s];
    int K = Ks[s], N = Ns[s];
    int n = e / K, k = e - n * K;
    dst[t] = f2bf(srcs[s][k * N + n]);
}

// ---- CSR build: histogram, scan, fill -------------------------------------
__global__ __launch_bounds__(256) void hist_kernel(const int* __restrict__ eidx,
                                                   int* __restrict__ deg)
{
    int e = blockIdx.x * 256 + threadIdx.x;
    if (e < E_TOTAL) atomicAdd(&deg[eidx[E_TOTAL + e]], 1);
}

__global__ __launch_bounds__(256) void scan_kernel(const int* __restrict__ deg,
                                                   int* __restrict__ off,
                                                   int* __restrict__ cur)
{
    __shared__ int sums[256];
    const int t = threadIdx.x;
    const int CH = (NN + 255) / 256;   // 196
    int s0 = t * CH, s1 = s0 + CH;
    if (s0 > NN) s0 = NN;
    if (s1 > NN) s1 = NN;
    int sum = 0;
    for (int i = s0; i < s1; ++i) sum += deg[i];
    sums[t] = sum;
    __syncthreads();
    // Hillis-Steele inclusive scan over 256 partials (8 steps)
    for (int d = 1; d < 256; d <<= 1) {
        int v = (t >= d) ? sums[t - d] : 0;
        __syncthreads();
        sums[t] += v;
        __syncthreads();
    }
    int base = (t == 0) ? 0 : sums[t - 1];
    for (int i = s0; i < s1; ++i) {
        off[i] = base; cur[i] = base;
        base += deg[i];
    }
    if (t == 255) off[NN] = sums[255];
}

__global__ __launch_bounds__(256) void fill_kernel(const int* __restrict__ eidx,
                                                   int* __restrict__ cur,
                                                   int* __restrict__ eid)
{
    int e = blockIdx.x * 256 + threadIdx.x;
    if (e < E_TOTAL) {
        int c = eidx[E_TOTAL + e];
        int p = atomicAdd(&cur[c], 1);
        eid[p] = e;
    }
}

// ---- edge kernel: 64 edges per block, fused 4-layer MLP (no scatter) ------
__global__ __launch_bounds__(256) void edge_kernel(
    const float* __restrict__ h, const int* __restrict__ eidx,
    const float* __restrict__ ea, const u16* __restrict__ wt,
    const float* __restrict__ eb0, const float* __restrict__ eb1,
    const float* __restrict__ eb2, const float* __restrict__ eb3,
    float* __restrict__ out_edge)
{
    __shared__ u16 Xs[64 * 200];   // [64][192] pad->200; reused as ping-pong buf
    __shared__ u16 Ha[64 * 136];   // [64][128] pad->136
    __shared__ int row_s[64], col_s[64];

    const int tid = threadIdx.x;
    const int ebase = blockIdx.x * 64;

    if (tid < 64)       row_s[tid] = eidx[ebase + tid];
    else if (tid < 128) col_s[tid - 64] = eidx[E_TOTAL + ebase + (tid - 64)];
    __syncthreads();

    // gather + f32->bf16: cols 0..63 = h[row], 64..127 = h[col], 128..191 = ea
#pragma unroll
    for (int g = tid; g < 1024; g += 256) {
        int e = g >> 4, c = g & 15;
        *(uint2*)&Xs[e * 200 + c * 4] = cvt4(h + (size_t)row_s[e] * 64 + c * 4);
    }
#pragma unroll
    for (int g = tid; g < 1024; g += 256) {
        int e = g >> 4, c = g & 15;
        *(uint2*)&Xs[e * 200 + 64 + c * 4] = cvt4(h + (size_t)col_s[e] * 64 + c * 4);
    }
#pragma unroll
    for (int g = tid; g < 1024; g += 256) {
        int e = g >> 4, c = g & 15;
        *(uint2*)&Xs[e * 200 + 128 + c * 4] = cvt4(ea + (size_t)(ebase + e) * 64 + c * 4);
    }
    __syncthreads();

    const int wave = tid >> 6, lane = tid & 63;
    const int w16 = wave * 16;
    const u16* wtE0 = wt;
    const u16* wtE1 = wt + 24576;
    const u16* wtE2 = wt + 40960;
    const u16* wtE3 = wt + 57344;

    // wave-private row slabs: Xs/Ha ping-pong, no inter-layer barriers needed
    layer_slab<192, 128, true>(Xs + w16 * 200, 200, Ha + w16 * 136, 136, wtE0, eb0, lane);
    layer_slab<128, 128, true>(Ha + w16 * 136, 136, Xs + w16 * 200, 200, wtE1, eb1, lane);
    layer_slab<128, 128, true>(Xs + w16 * 200, 200, Ha + w16 * 136, 136, wtE2, eb2, lane);

    // final layer K=128 N=64, no relu; write edge_out (scatter handled by CSR gather)
    {
        const u16* in = Ha + w16 * 136;
        const int m = lane & 15, quad = lane >> 4;
        short8 a[4];
#pragma unroll
        for (int kb = 0; kb < 4; ++kb)
            a[kb] = *(const short8*)(in + m * 136 + kb * 32 + quad * 8);
#pragma unroll
        for (int np = 0; np < 2; ++np) {
            floatx4 acc0 = {0, 0, 0, 0}, acc1 = {0, 0, 0, 0};
            const int n0 = np * 32 + m, n1 = n0 + 16;
#pragma unroll
            for (int kb = 0; kb < 4; ++kb) {
                short8 b0 = *(const short8*)(wtE3 + n0 * 128 + kb * 32 + quad * 8);
                short8 b1 = *(const short8*)(wtE3 + n1 * 128 + kb * 32 + quad * 8);
                acc0 = __builtin_amdgcn_mfma_f32_16x16x32_bf16(a[kb], b0, acc0, 0, 0, 0);
                acc1 = __builtin_amdgcn_mfma_f32_16x16x32_bf16(a[kb], b1, acc1, 0, 0, 0);
            }
            float bb0 = eb3[n0], bb1 = eb3[n1];
#pragma unroll
            for (int r = 0; r < 4; ++r) {
                int rl = w16 + quad * 4 + r;
                size_t e = (size_t)(ebase + rl);
                out_edge[e * 64 + n0] = acc0[r] + bb0;
                out_edge[e * 64 + n1] = acc1[r] + bb1;
            }
        }
    }
}

// ---- node kernel: 64 nodes per block; CSR gather of msg + 4-layer MLP ------
__global__ __launch_bounds__(256) void node_kernel(
    const float* __restrict__ h, const float* __restrict__ edge_out,
    const int* __restrict__ off, const int* __restrict__ eid,
    const u16* __restrict__ wt,
    const float* __restrict__ nb0, const float* __restrict__ nb1,
    const float* __restrict__ nb2, const float* __restrict__ nb3,
    float* __restrict__ out_node)
{
    __shared__ u16 Xs[64 * 136];
    __shared__ u16 Ha[64 * 136];

    const int tid = threadIdx.x;
    const int nbase = blockIdx.x * 64;

    // h -> cols 0..63 (cooperative across waves)
#pragma unroll
    for (int g = tid; g < 1024; g += 256) {
        int e = g >> 4, c = g & 15;
        int node = nbase + e;
        uint2 v = {0u, 0u};
        if (node < NN) v = cvt4(h + (size_t)node * 64 + c * 4);
        *(uint2*)&Xs[e * 136 + c * 4] = v;
    }
    // msg gather-sum -> cols 64..127: 4 threads per node, 16 floats each
    {
        const int row = tid >> 2, p = tid & 3;
        const int node = nbase + row;
        floatx4 a0 = {0, 0, 0, 0}, a1 = {0, 0, 0, 0};
        floatx4 a2 = {0, 0, 0, 0}, a3 = {0, 0, 0, 0};
        if (node < NN) {
            int s = off[node], e1 = off[node + 1];
            for (int j = s; j < e1; ++j) {
                const floatx4* src =
                    (const floatx4*)(edge_out + (size_t)eid[j] * 64 + p * 16);
                a0 += src[0]; a1 += src[1]; a2 += src[2]; a3 += src[3];
            }
        }
        u16* dst = Xs + row * 136 + 64 + p * 16;
        ((uint2*)dst)[0] = packf4(a0);
        ((uint2*)dst)[1] = packf4(a1);
        ((uint2*)dst)[2] = packf4(a2);
        ((uint2*)dst)[3] = packf4(a3);
    }
    __syncthreads();

    const int wave = tid >> 6, lane = tid & 63;
    const int w16 = wave * 16;
    const u16* wtN0 = wt + 65536;
    const u16* wtN1 = wt + 81920;
    const u16* wtN2 = wt + 98304;
    const u16* wtN3 = wt + 114688;

    layer_slab<128, 128, true>(Xs + w16 * 136, 136, Ha + w16 * 136, 136, wtN0, nb0, lane);
    layer_slab<128, 128, true>(Ha + w16 * 136, 136, Xs + w16 * 136, 136, wtN1, nb1, lane);
    layer_slab<128, 128, true>(Xs + w16 * 136, 136, Ha + w16 * 136, 136, wtN2, nb2, lane);

    {
        const u16* in = Ha + w16 * 136;
        const int m = lane & 15, quad = lane >> 4;
        short8 a[4];
#pragma unroll
        for (int kb = 0; kb < 4; ++kb)
            a[kb] = *(const short8*)(in + m * 136 + kb * 32 + quad * 8);
#pragma unroll
        for (int np = 0; np < 2; ++np) {
            floatx4 acc0 = {0, 0, 0, 0}, acc1 = {0, 0, 0, 0};
            const int n0 = np * 32 + m, n1 = n0 + 16;
#pragma unroll
            for (int kb = 0; kb < 4; ++kb) {
                short8 b0 = *(const short8*)(wtN3 + n0 * 128 + kb * 32 + quad * 8);
                short8 b1 = *(const short8*)(wtN3 + n1 * 128 + kb * 32 + quad * 8);
                acc0 = __builtin_amdgcn_mfma_f32_16x16x32_bf16(a[kb], b0, acc0, 0, 0, 0);
                acc1 = __builtin_amdgcn_mfma_f32_16x16x32_bf16(a[kb], b1, acc1, 0, 0, 0);
            }
            float bb0 = nb3[n0], bb1 = nb3[n1];
#pragma unroll
            for (int r = 0; r < 4; ++r) {
                int rl = w16 + quad * 4 + r;
                int node = nbase + rl;
                if (node < NN) {
                    out_node[(size_t)node * 64 + n0] = acc0[r] + bb0;
                    out_node[(size_t)node * 64 + n1] = acc1[r] + bb1;
                }
            }
        }
    }
}

extern "C" void kernel_launch(void* const* d_in, const int* in_sizes, int n_in,
                              void* d_out, int out_size, void* d_ws, size_t ws_size,
                              hipStream_t stream)
{
    // setup_inputs() dict order: h, edge_index, edge_attr, then per i:
    // ew{i}, eb{i}, nw{i}, nb{i}
    const float* h   = (const float*)d_in[0];
    const int* eidx  = (const int*)d_in[1];
    const float* ea  = (const float*)d_in[2];
    const float* ew0 = (const float*)d_in[3];
    const float* eb0 = (const float*)d_in[4];
    const float* nw0 = (const float*)d_in[5];
    const float* nb0 = (const float*)d_in[6];
    const float* ew1 = (const float*)d_in[7];
    const float* eb1 = (const float*)d_in[8];
    const float* nw1 = (const float*)d_in[9];
    const float* nb1 = (const float*)d_in[10];
    const float* ew2 = (const float*)d_in[11];
    const float* eb2 = (const float*)d_in[12];
    const float* nw2 = (const float*)d_in[13];
    const float* nb2 = (const float*)d_in[14];
    const float* ew3 = (const float*)d_in[15];
    const float* eb3 = (const float*)d_in[16];
    const float* nw3 = (const float*)d_in[17];
    const float* nb3 = (const float*)d_in[18];

    // workspace layout (wt FIRST so its 16-byte alignment is guaranteed):
    // wt[122880 u16] | deg[50000] | off[50001] | cur[50001] | eid[800000]
    u16* wt  = (u16*)d_ws;
    int* deg = (int*)((char*)d_ws + WT_BYTES);
    int* off = deg + NN;
    int* cur = off + NN + 1;
    int* eid = cur + NN + 1;

    float* out_node = (float*)d_out;
    float* out_edge = out_node + (size_t)NN * 64;

    hipMemsetAsync(deg, 0, NN * sizeof(int), stream);
    prep_wt<<<480, 256, 0, stream>>>(ew0, ew1, ew2, ew3, nw0, nw1, nw2, nw3, wt);
    hist_kernel<<<(E_TOTAL + 255) / 256, 256, 0, stream>>>(eidx, deg);
    scan_kernel<<<1, 256, 0, stream>>>(deg, off, cur);
    fill_kernel<<<(E_TOTAL + 255) / 256, 256, 0, stream>>>(eidx, cur, eid);
    edge_kernel<<<E_TOTAL / 64, 256, 0, stream>>>(h, eidx, ea, wt,
                                                  eb0, eb1, eb2, eb3, out_edge);
    node_kernel<<<(NN + 63) / 64, 256, 0, stream>>>(h, out_edge, off, eid, wt,
                                                    nb0, nb1, nb2, nb3, out_node);
}